// Round 7
// baseline (79.889 us; speedup 1.0000x reference)
//
#include <hip/hip_runtime.h>
#include <hip/hip_fp16.h>

// SSIM loss, v-first separable Gaussian (11 taps, sigma=1.5), zero LDS.
// Each wave owns a 16-row x 116-col output strip (5 overlapping strips per
// 512 cols). Ring holds 11 RAW rows of x,y (22 half2 regs). Per output row:
// v-conv from ring (packed f16), then h-conv on the 5 v-maps via cross-lane
// shuffles (+alignbit for odd offsets), SSIM formula in f32. Wave-edge and
// out-of-image lanes masked at accumulation.

#define R      16
#define NIT    (R + 10)          // 26 staged rows per strip
#define NSTRIP (48 * 32 * 5)     // 7680 waves
#define NBLK   (NSTRIP / 4)      // 1920 blocks
#define NPIX   12582912.0        // 16*3*512*512

static __device__ __forceinline__ unsigned fun16(unsigned hi, unsigned lo) {
    return (unsigned)((((unsigned long long)hi << 32) | lo) >> 16);  // v_alignbit
}
static __device__ __forceinline__ unsigned h2u(__half2 v) {
    unsigned u; __builtin_memcpy(&u, &v, 4); return u;
}
static __device__ __forceinline__ __half2 u2h(unsigned u) {
    __half2 v; __builtin_memcpy(&v, &u, 4); return v;
}

__global__ __launch_bounds__(256) void ssim_vh_kernel(
    const float* __restrict__ X, const float* __restrict__ Y,
    float* __restrict__ partial)
{
    const int tid  = threadIdx.x;
    const int lane = tid & 63;
    const int w    = tid >> 6;
    const int sid  = blockIdx.x * 4 + w;
    const int img  = sid / 160;          // 32 bands * 5 strips
    const int rem  = sid - img * 160;
    const int band = rem / 5;
    const int s    = rem - band * 5;
    const int r0   = band * R;
    const int oc   = 116 * s - 6;        // word col origin (even)
    const int c2   = oc + 2 * lane;      // own 2 cols

    const float* __restrict__ Xi = X + (size_t)img * (512 * 512);
    const float* __restrict__ Yi = Y + (size_t)img * (512 * 512);

    // Gaussian weights (matches jnp construction)
    float g[11];
    {
        float sum = 0.f;
        #pragma unroll
        for (int i = 0; i < 11; ++i) {
            float d = (float)(i - 5);
            float e = expf(-d * d * (1.0f / 4.5f));
            g[i] = e; sum += e;
        }
        float inv = 1.0f / sum;
        #pragma unroll
        for (int i = 0; i < 11; ++i) g[i] *= inv;
    }
    __half2 w2[11];
    #pragma unroll
    for (int i = 0; i < 11; ++i) w2[i] = __float2half2_rn(g[i]);

    const bool  cok = ((unsigned)c2 < 512u);                       // word in image
    const float msk = (lane >= 3 && lane <= 60 && cok) ? 1.f : 0.f; // output valid

    // h-conv on one v-map word via cross-lane shuffles (words l-3..l+3)
    auto hconv = [&](__half2 vown) -> __half2 {
        const unsigned W3  = h2u(vown);
        const unsigned Wm3 = (unsigned)__shfl((int)W3, lane - 3, 64);
        const unsigned Wm2 = (unsigned)__shfl((int)W3, lane - 2, 64);
        const unsigned Wm1 = (unsigned)__shfl((int)W3, lane - 1, 64);
        const unsigned Wp1 = (unsigned)__shfl((int)W3, lane + 1, 64);
        const unsigned Wp2 = (unsigned)__shfl((int)W3, lane + 2, 64);
        const unsigned Wp3 = (unsigned)__shfl((int)W3, lane + 3, 64);
        __half2 h = __hmul2(w2[0], u2h(fun16(Wm2, Wm3)));
        h = __hfma2(w2[1],  u2h(Wm2),            h);
        h = __hfma2(w2[2],  u2h(fun16(Wm1, Wm2)), h);
        h = __hfma2(w2[3],  u2h(Wm1),            h);
        h = __hfma2(w2[4],  u2h(fun16(W3,  Wm1)), h);
        h = __hfma2(w2[5],  vown,                h);
        h = __hfma2(w2[6],  u2h(fun16(Wp1, W3)),  h);
        h = __hfma2(w2[7],  u2h(Wp1),            h);
        h = __hfma2(w2[8],  u2h(fun16(Wp2, Wp1)), h);
        h = __hfma2(w2[9],  u2h(Wp2),            h);
        h = __hfma2(w2[10], u2h(fun16(Wp3, Wp2)), h);
        return h;
    };

    // prologue: load row j=0
    float2 nx = make_float2(0.f, 0.f), ny = nx;
    {
        const int gr = r0 - 5;
        if ((unsigned)gr < 512u && cok) {
            nx = *(const float2*)(Xi + (size_t)gr * 512 + c2);
            ny = *(const float2*)(Yi + (size_t)gr * 512 + c2);
        }
    }

    __half2 rx[11], ry[11];      // raw-row ring — static indices only
    float acc = 0.f;
    const __half2 hz = __float2half2_rn(0.f);
    const float C1 = 1e-4f, C2 = 9e-4f;

    #pragma unroll 1
    for (int jb = 0; jb < 33; jb += 11) {
        #pragma unroll
        for (int ph = 0; ph < 11; ++ph) {
            const int j = jb + ph;            // j % 11 == ph
            if (j < NIT) {
                // push current row (loaded last iter) into ring
                rx[ph] = __floats2half2_rn(nx.x, nx.y);
                ry[ph] = __floats2half2_rn(ny.x, ny.y);

                // prefetch next row (hide HBM/L2 latency under the math)
                if (j + 1 < NIT) {
                    const int gr = r0 - 4 + j;
                    nx = make_float2(0.f, 0.f); ny = nx;
                    if ((unsigned)gr < 512u && cok) {
                        nx = *(const float2*)(Xi + (size_t)gr * 512 + c2);
                        ny = *(const float2*)(Yi + (size_t)gr * 512 + c2);
                    }
                }

                if (j >= 10) {
                    // v-conv from raw ring (5 maps, packed f16)
                    __half2 vx = hz, vy = hz, vxx = hz, vyy = hz, vxy = hz;
                    #pragma unroll
                    for (int k = 0; k < 11; ++k) {
                        const int sl = (ph + 1 + k) % 11;
                        const __half2 xk = rx[sl], yk = ry[sl];
                        const __half2 wx = __hmul2(w2[k], xk);
                        const __half2 wy = __hmul2(w2[k], yk);
                        vx  = __hadd2(vx, wx);
                        vy  = __hadd2(vy, wy);
                        vxx = __hfma2(wx, xk, vxx);
                        vyy = __hfma2(wy, yk, vyy);
                        vxy = __hfma2(wx, yk, vxy);
                    }

                    // h-conv on the 5 v-maps (in-register, cross-lane)
                    const __half2 hm1 = hconv(vx);
                    const __half2 hm2 = hconv(vy);
                    const __half2 hxx = hconv(vxx);
                    const __half2 hyy = hconv(vyy);
                    const __half2 hxy = hconv(vxy);

                    // SSIM formula (f32) on this lane's 2 cols
                    const float2 m1 = __half22float2(hm1);
                    const float2 m2 = __half22float2(hm2);
                    const float2 xx = __half22float2(hxx);
                    const float2 yy = __half22float2(hyy);
                    const float2 xy = __half22float2(hxy);
                    float val = 0.f;
                    #pragma unroll
                    for (int h = 0; h < 2; ++h) {
                        const float a1 = h ? m1.y : m1.x;
                        const float a2 = h ? m2.y : m2.x;
                        const float bx = h ? xx.y : xx.x;
                        const float by = h ? yy.y : yy.x;
                        const float bz = h ? xy.y : xy.x;
                        const float m11 = a1 * a1, m22 = a2 * a2, m12 = a1 * a2;
                        const float s1 = bx - m11, s2 = by - m22, s12 = bz - m12;
                        const float num = (2.f * m12 + C1) * (2.f * s12 + C2);
                        const float den = (m11 + m22 + C1) * (s1 + s2 + C2);
                        val = fmaf(num, __builtin_amdgcn_rcpf(den), val);
                    }
                    acc = fmaf(msk, val, acc);   // mask wave-edge / OOB lanes
                }
            }
        }
    }

    // wave reduction; each wave owns its strip's partial
    #pragma unroll
    for (int off = 32; off > 0; off >>= 1)
        acc += __shfl_down(acc, off, 64);
    if (lane == 0) partial[sid] = acc;
}

__global__ __launch_bounds__(256) void ssim_reduce_kernel(
    const float* __restrict__ partial, float* __restrict__ out)
{
    const int tid = threadIdx.x;
    double s = 0.0;
    for (int i = tid; i < NSTRIP; i += 256) s += (double)partial[i];
    __shared__ double sd[256];
    sd[tid] = s;
    __syncthreads();
    for (int off = 128; off > 0; off >>= 1) {
        if (tid < off) sd[tid] += sd[tid + off];
        __syncthreads();
    }
    if (tid == 0) out[0] = (float)(1.0 - sd[0] / NPIX);
}

extern "C" void kernel_launch(void* const* d_in, const int* in_sizes, int n_in,
                              void* d_out, int out_size, void* d_ws, size_t ws_size,
                              hipStream_t stream) {
    const float* X = (const float*)d_in[0];
    const float* Y = (const float*)d_in[1];
    float* partial = (float*)d_ws;   // NSTRIP floats = 30 KiB
    float* out = (float*)d_out;

    ssim_vh_kernel<<<NBLK, 256, 0, stream>>>(X, Y, partial);
    ssim_reduce_kernel<<<1, 256, 0, stream>>>(partial, out);
}